// Round 6
// baseline (4605.314 us; speedup 1.0000x reference)
//
#include <hip/hip_runtime.h>

typedef _Float16 f16;
typedef _Float16 f16x8 __attribute__((ext_vector_type(8)));
typedef float    f32x4 __attribute__((ext_vector_type(4)));
typedef unsigned long long u64;

#define TSEQ 128
#define PRED 10

// ---------------- small utility kernels ----------------
__global__ void k_cvt(const float* __restrict__ src, f16* __restrict__ dst, int n) {
  int i = blockIdx.x * blockDim.x + threadIdx.x;
  int stride = gridDim.x * blockDim.x;
  for (; i < n; i += stride) dst[i] = (f16)src[i];
}

__global__ void k_bias(const float* __restrict__ a, const float* __restrict__ b,
                       float* __restrict__ o, int n) {
  int i = blockIdx.x * blockDim.x + threadIdx.x;
  if (i < n) o[i] = a[i] + b[i];
}

// ---------------- wavefront encoder, consumer-side transform ----------------
// 512 blocks = 32 clusters(c: 32 batch rows) x 4 subs(128 cols) x 4 layers.
// bid = c*16 + sub*4 + layer  ->  exactly 2 blocks/CU (all resident); any
// resident prefix is whole clusters (bid-contiguous) -> no deadlock.
// layer = bid&3 -> each XCD pair hosts one layer's weights in L2 (~2 MB).
// Per step: layer l gathers own h_{t-1} AND upstream h^{l-1}_t (concurrent L3
// round trips), then acc = h^{l-1}_t@Wih_l + h_{t-1}@Whh_l (both weight
// operands streamed from L2 - the compiler does this anyway, see R5), tanh,
// publish into a depth-4 slot ring guarded by a consumed-counter.
// Waits: own ctr >= 4t, upstream ctr >= 4(t+1), producers check cons >= 4(t-3)
// (prefetched at step start). All waits point backward in wavefront time.
__global__ __launch_bounds__(256) void k_enc_wave(
    const float* __restrict__ x, const float* __restrict__ Wih0,
    const f16* __restrict__ eWih, const float* __restrict__ encB,
    const f16* __restrict__ eWhh, float* __restrict__ out_f,
    f16* __restrict__ hT, u64* __restrict__ hx,
    int* __restrict__ ctr, int* __restrict__ cons) {
  __shared__ f16 As[32 * 520];   // one h tile (rows=32), stride 520 keeps 16B align
  __shared__ float xs[32][8];    // layer-0 raw input rows
  const int tid = threadIdx.x;
  const int w = tid >> 6, lane = tid & 63, q = lane >> 4, l15 = lane & 15;
  const int bid = blockIdx.x;
  const int layer = bid & 3, sub = (bid >> 2) & 3, c = bid >> 4;  // c in [0,32)
  const int row0 = c * 32, ncol0 = sub * 128 + w * 32;
  const int is_l0 = (layer == 0), is_top = (layer == 3);
  int* myctr = ctr + (layer * 32 + c) * 32;
  int* upctr = is_l0 ? nullptr : ctr + ((layer - 1) * 32 + c) * 32;
  int* mycons = is_l0 ? nullptr : cons + ((layer - 1) * 32 + c) * 32;  // I consume iface layer-1
  int* pcons  = is_top ? nullptr : cons + (layer * 32 + c) * 32;       // my consumers' counter
  const f16* Whh = eWhh + (size_t)layer * 262144;
  const f16* Wt  = is_l0 ? (const f16*)nullptr : eWih + (size_t)(layer - 1) * 262144;
  u64* HXmy = hx + (size_t)layer * 524288;           // 4 slots * 32 c * 4096 u64
  u64* HXup = is_l0 ? nullptr : hx + (size_t)(layer - 1) * 524288;
  f16* myhT = hT + (size_t)layer * 524288;

  float w0[2][6], b0[2], tb[2];
  if (is_l0) {
#pragma unroll
    for (int ct = 0; ct < 2; ct++) {
      int ng = ncol0 + ct * 16 + l15;
#pragma unroll
      for (int d = 0; d < 6; d++) w0[ct][d] = Wih0[ng * 6 + d];
      b0[ct] = encB[ng];
    }
  } else {
    tb[0] = encB[layer * 512 + ncol0 + l15];
    tb[1] = encB[layer * 512 + ncol0 + 16 + l15];
  }

  for (int i = tid; i < 32 * 520; i += 256) As[i] = (f16)0.0f;
  if (is_l0 && tid < 192)
    xs[tid / 6][tid % 6] = x[((size_t)(row0 + tid / 6) * TSEQ + 0) * 6 + tid % 6];
  __syncthreads();

  const int k0 = tid * 2;  // this thread's two gather columns

  for (int t = 0; t < TSEQ; t++) {
    // prefetch the backpressure counter (checked just before publish)
    int pcv = 0x7fffffff;
    if (pcons && t >= 4)
      pcv = __hip_atomic_load(pcons, __ATOMIC_RELAXED, __HIP_MEMORY_SCOPE_AGENT);

    // wait: own cluster published h_{t-1}; upstream published h_t
    if (tid == 0) {
      if (t > 0)
        while (__hip_atomic_load(myctr, __ATOMIC_RELAXED, __HIP_MEMORY_SCOPE_AGENT) < 4 * t)
          __builtin_amdgcn_s_sleep(1);
      if (!is_l0)
        while (__hip_atomic_load(upctr, __ATOMIC_RELAXED, __HIP_MEMORY_SCOPE_AGENT) < 4 * (t + 1))
          __builtin_amdgcn_s_sleep(1);
    }
    __syncthreads();

    // issue upstream gather loads (stay in flight under own gather)
    u64 uv[16];
    if (!is_l0) {
      const u64* ub = HXup + ((size_t)(t & 3) * 32 + c) * 4096 + (size_t)k0 * 8;
#pragma unroll
      for (int j = 0; j < 16; j++)
        uv[j] = __hip_atomic_load(ub + j, __ATOMIC_RELAXED, __HIP_MEMORY_SCOPE_AGENT);
    }
    // gather own h_{t-1} into As
    if (t > 0) {
      u64 ov[16];
      const u64* ob = HXmy + ((size_t)((t - 1) & 3) * 32 + c) * 4096 + (size_t)k0 * 8;
#pragma unroll
      for (int j = 0; j < 16; j++)
        ov[j] = __hip_atomic_load(ob + j, __ATOMIC_RELAXED, __HIP_MEMORY_SCOPE_AGENT);
      union U { u64 u[8]; f16 h[32]; } u0, u1;
#pragma unroll
      for (int j = 0; j < 8; j++) { u0.u[j] = ov[j]; u1.u[j] = ov[8 + j]; }
#pragma unroll
      for (int row = 0; row < 32; row++) {
        union { f16 h2[2]; unsigned int wv; } pw;
        pw.h2[0] = u0.h[row]; pw.h2[1] = u1.h[row];
        *(unsigned int*)&As[row * 520 + k0] = pw.wv;
      }
      if (is_l0 && tid < 192)
        xs[tid / 6][tid % 6] = x[((size_t)(row0 + tid / 6) * TSEQ + t) * 6 + tid % 6];
    }
    __syncthreads();

    // pass 1: recurrence  acc += h_{t-1} @ Whh^T
    const f32x4 zero = {0.f, 0.f, 0.f, 0.f};
    f32x4 acc[2][2] = {{zero, zero}, {zero, zero}};  // [mt][ct]
    {
      const f16* bp0 = &Whh[(size_t)(ncol0 + l15) * 512 + q * 8];
      const f16* bp1 = &Whh[(size_t)(ncol0 + 16 + l15) * 512 + q * 8];
#pragma unroll
      for (int kk = 0; kk < 16; kk++) {
        f16x8 a0 = *(const f16x8*)&As[l15 * 520 + kk * 32 + q * 8];
        f16x8 a1 = *(const f16x8*)&As[(16 + l15) * 520 + kk * 32 + q * 8];
        f16x8 b0v = *(const f16x8*)(bp0 + kk * 32);
        f16x8 b1v = *(const f16x8*)(bp1 + kk * 32);
        acc[0][0] = __builtin_amdgcn_mfma_f32_16x16x32_f16(a0, b0v, acc[0][0], 0, 0, 0);
        acc[0][1] = __builtin_amdgcn_mfma_f32_16x16x32_f16(a0, b1v, acc[0][1], 0, 0, 0);
        acc[1][0] = __builtin_amdgcn_mfma_f32_16x16x32_f16(a1, b0v, acc[1][0], 0, 0, 0);
        acc[1][1] = __builtin_amdgcn_mfma_f32_16x16x32_f16(a1, b1v, acc[1][1], 0, 0, 0);
      }
    }

    // pass 2: input transform  acc += h^{l-1}_t @ Wih^T   (layers 1..3)
    if (!is_l0) {
      __syncthreads();  // pass-1 reads of As done
      union U { u64 u[8]; f16 h[32]; } u0, u1;
#pragma unroll
      for (int j = 0; j < 8; j++) { u0.u[j] = uv[j]; u1.u[j] = uv[8 + j]; }
#pragma unroll
      for (int row = 0; row < 32; row++) {
        union { f16 h2[2]; unsigned int wv; } pw;
        pw.h2[0] = u0.h[row]; pw.h2[1] = u1.h[row];
        *(unsigned int*)&As[row * 520 + k0] = pw.wv;
      }
      __syncthreads();
      const f16* wp0 = &Wt[(size_t)(ncol0 + l15) * 512 + q * 8];
      const f16* wp1 = &Wt[(size_t)(ncol0 + 16 + l15) * 512 + q * 8];
#pragma unroll
      for (int kk = 0; kk < 16; kk++) {
        f16x8 a0 = *(const f16x8*)&As[l15 * 520 + kk * 32 + q * 8];
        f16x8 a1 = *(const f16x8*)&As[(16 + l15) * 520 + kk * 32 + q * 8];
        f16x8 b0v = *(const f16x8*)(wp0 + kk * 32);
        f16x8 b1v = *(const f16x8*)(wp1 + kk * 32);
        acc[0][0] = __builtin_amdgcn_mfma_f32_16x16x32_f16(a0, b0v, acc[0][0], 0, 0, 0);
        acc[0][1] = __builtin_amdgcn_mfma_f32_16x16x32_f16(a0, b1v, acc[0][1], 0, 0, 0);
        acc[1][0] = __builtin_amdgcn_mfma_f32_16x16x32_f16(a1, b0v, acc[1][0], 0, 0, 0);
        acc[1][1] = __builtin_amdgcn_mfma_f32_16x16x32_f16(a1, b1v, acc[1][1], 0, 0, 0);
      }
    }

    // tanh + pack
    float hv[2][2][4];
    union { u64 u; f16 h4[4]; } pk[2][2];
#pragma unroll
    for (int ct = 0; ct < 2; ct++)
#pragma unroll
      for (int mt = 0; mt < 2; mt++)
#pragma unroll
        for (int r = 0; r < 4; r++) {
          int m = mt * 16 + q * 4 + r;
          float pre;
          if (is_l0) {
            float xwv = b0[ct];
#pragma unroll
            for (int d = 0; d < 6; d++) xwv += xs[m][d] * w0[ct][d];
            pre = acc[mt][ct][r] + xwv;
          } else {
            pre = acc[mt][ct][r] + tb[ct];
          }
          hv[ct][mt][r] = tanhf(pre);
          pk[ct][mt].h4[r] = (f16)hv[ct][mt][r];
        }

    // backpressure: slot t&3 must be fully consumed (h_{t-4})
    if (pcons && t >= 4 && pcv < 4 * (t - 3)) {
      while (__hip_atomic_load(pcons, __ATOMIC_RELAXED, __HIP_MEMORY_SCOPE_AGENT) < 4 * (t - 3))
        __builtin_amdgcn_s_sleep(1);
    }

    // publish h_t
    {
      u64* pb = HXmy + ((size_t)(t & 3) * 32 + c) * 4096;
#pragma unroll
      for (int ct = 0; ct < 2; ct++)
#pragma unroll
        for (int mt = 0; mt < 2; mt++)
          __hip_atomic_store(pb + (size_t)(ncol0 + ct * 16 + l15) * 8 + mt * 4 + q,
                             pk[ct][mt].u, __ATOMIC_RELAXED, __HIP_MEMORY_SCOPE_AGENT);
    }
    __builtin_amdgcn_s_waitcnt(0);
    __syncthreads();
    if (tid == 0) {
      __hip_atomic_fetch_add(myctr, 1, __ATOMIC_RELAXED, __HIP_MEMORY_SCOPE_AGENT);
      if (!is_l0)
        __hip_atomic_fetch_add(mycons, 1, __ATOMIC_RELAXED, __HIP_MEMORY_SCOPE_AGENT);
    }

    // outputs (off the sync critical path)
    if (is_top) {
#pragma unroll
      for (int ct = 0; ct < 2; ct++)
#pragma unroll
        for (int mt = 0; mt < 2; mt++)
#pragma unroll
          for (int r = 0; r < 4; r++)
            out_f[((size_t)(row0 + mt * 16 + q * 4 + r) * TSEQ + t) * 512 +
                  (ncol0 + ct * 16 + l15)] = hv[ct][mt][r];
    }
    if (t == TSEQ - 1) {
#pragma unroll
      for (int ct = 0; ct < 2; ct++)
#pragma unroll
        for (int mt = 0; mt < 2; mt++)
#pragma unroll
          for (int r = 0; r < 4; r++)
            myhT[(size_t)(row0 + mt * 16 + q * 4 + r) * 512 + ncol0 + ct * 16 + l15] =
                pk[ct][mt].h4[r];
    }
  }
}

// ---------------- decoder (proven baseline, counter protocol) ----------------
__global__ __launch_bounds__(256) void k_dec_rec(
    const f16* __restrict__ Wih, const f16* __restrict__ Whh,
    const float* __restrict__ decB, const f16* __restrict__ hT,
    f16* __restrict__ hstate, f16* __restrict__ dec_out, int* __restrict__ ctr) {
  __shared__ f16 xb[16 * 520];
  __shared__ f16 hb[16 * 520];
  const int tid = threadIdx.x;
  const int w = tid >> 6, lane = tid & 63, q = lane >> 4, l15 = lane & 15;
  const int c = blockIdx.x >> 2, sub = blockIdx.x & 3;
  const int row0 = c * 16;
  const int ncol0 = sub * 128 + w * 32;
  int* myctr = ctr + c * 32;
  const size_t LSZ = (size_t)1024 * 512;

  auto load_rm = [&](f16* dst, const f16* src) {
#pragma unroll
    for (int i = 0; i < 4; i++) {
      int idx = tid + 256 * i; int m = idx >> 6, kc = idx & 63;
      *(f16x8*)&dst[m * 520 + kc * 8] = *(const f16x8*)&src[(size_t)(row0 + m) * 512 + kc * 8];
    }
  };
  auto load_cm = [&](f16* dst, int buf) {
    u64 v[8];
#pragma unroll
    for (int cc = 0; cc < 2; cc++) {
      int col = tid * 2 + cc;
      const u64* bp = (const u64*)&hstate[(((size_t)buf * 64 + c) * 512 + col) * 16];
#pragma unroll
      for (int j = 0; j < 4; j++)
        v[cc * 4 + j] = __hip_atomic_load(bp + j, __ATOMIC_RELAXED, __HIP_MEMORY_SCOPE_AGENT);
    }
    union { u64 u[4]; f16 h[16]; } un0, un1;
    un0.u[0] = v[0]; un0.u[1] = v[1]; un0.u[2] = v[2]; un0.u[3] = v[3];
    un1.u[0] = v[4]; un1.u[1] = v[5]; un1.u[2] = v[6]; un1.u[3] = v[7];
#pragma unroll
    for (int k = 0; k < 16; k++) {
      union { f16 h2[2]; unsigned int u; } pw;
      pw.h2[0] = un0.h[k]; pw.h2[1] = un1.h[k];
      *(unsigned int*)&dst[k * 520 + tid * 2] = pw.u;
    }
  };

  for (int s = 0; s < PRED; s++) {
    int wb = (s + 1) & 1, rb = s & 1;
    for (int l = 0; l < 4; l++) {
      const bool last = (s == PRED - 1) && (l == 3);
      if (l == 0) {
        if (s == 0) load_rm(xb, hT + 3 * LSZ);
        else load_cm(xb, rb * 4 + 3);
      } else {
        load_cm(xb, wb * 4 + (l - 1));
      }
      if (s == 0) load_rm(hb, hT + (size_t)l * LSZ);
      else load_cm(hb, rb * 4 + l);
      __syncthreads();

      const f32x4 zero = {0.f, 0.f, 0.f, 0.f};
      f32x4 acc0 = zero, acc1 = zero;
      const f16* Wl = Wih + (size_t)l * 512 * 512;
      const f16* Ul = Whh + (size_t)l * 512 * 512;
      int ng0 = ncol0 + l15, ng1 = ncol0 + 16 + l15;
#pragma unroll
      for (int kk = 0; kk < 16; kk++) {
        f16x8 a = *(const f16x8*)&xb[l15 * 520 + kk * 32 + q * 8];
        f16x8 bv0 = *(const f16x8*)&Wl[(size_t)ng0 * 512 + kk * 32 + q * 8];
        f16x8 bv1 = *(const f16x8*)&Wl[(size_t)ng1 * 512 + kk * 32 + q * 8];
        acc0 = __builtin_amdgcn_mfma_f32_16x16x32_f16(a, bv0, acc0, 0, 0, 0);
        acc1 = __builtin_amdgcn_mfma_f32_16x16x32_f16(a, bv1, acc1, 0, 0, 0);
      }
#pragma unroll
      for (int kk = 0; kk < 16; kk++) {
        f16x8 a = *(const f16x8*)&hb[l15 * 520 + kk * 32 + q * 8];
        f16x8 bv0 = *(const f16x8*)&Ul[(size_t)ng0 * 512 + kk * 32 + q * 8];
        f16x8 bv1 = *(const f16x8*)&Ul[(size_t)ng1 * 512 + kk * 32 + q * 8];
        acc0 = __builtin_amdgcn_mfma_f32_16x16x32_f16(a, bv0, acc0, 0, 0, 0);
        acc1 = __builtin_amdgcn_mfma_f32_16x16x32_f16(a, bv1, acc1, 0, 0, 0);
      }

      int obuf = wb * 4 + l;
      union { u64 u; f16 h4[4]; } pk[2];
#pragma unroll
      for (int t2 = 0; t2 < 2; t2++) {
        f32x4 accv = t2 ? acc1 : acc0;
        int ng = ncol0 + t2 * 16 + l15;
#pragma unroll
        for (int r = 0; r < 4; r++)
          pk[t2].h4[r] = (f16)tanhf(accv[r] + decB[l * 512 + ng]);
      }

      if (!last) {
#pragma unroll
        for (int t2 = 0; t2 < 2; t2++) {
          int ng = ncol0 + t2 * 16 + l15;
          __hip_atomic_store(
              (u64*)&hstate[(((size_t)obuf * 64 + c) * 512 + ng) * 16 + q * 4],
              pk[t2].u, __ATOMIC_RELAXED, __HIP_MEMORY_SCOPE_AGENT);
        }
        __builtin_amdgcn_s_waitcnt(0);
        __syncthreads();
        if (tid == 0)
          __hip_atomic_fetch_add(myctr, 1, __ATOMIC_RELAXED, __HIP_MEMORY_SCOPE_AGENT);
      }

      if (l == 3) {
#pragma unroll
        for (int t2 = 0; t2 < 2; t2++) {
          int ng = ncol0 + t2 * 16 + l15;
#pragma unroll
          for (int r = 0; r < 4; r++)
            dec_out[((size_t)(row0 + q * 4 + r) * PRED + s) * 512 + ng] = pk[t2].h4[r];
        }
      }

      if (!last) {
        if (tid == 0) {
          int target = 4 * (s * 4 + l + 1);
          while (__hip_atomic_load(myctr, __ATOMIC_RELAXED, __HIP_MEMORY_SCOPE_AGENT) < target)
            __builtin_amdgcn_s_sleep(1);
        }
        __syncthreads();
      }
    }
  }
}

// ---------------- final FC ----------------
__global__ __launch_bounds__(256) void k_fc(
    const f16* __restrict__ dec_out, const float* __restrict__ fcW,
    const float* __restrict__ fcb, float* __restrict__ out) {
  __shared__ float Wl[6 * 512];
  __shared__ float bl[8];
  int tid = threadIdx.x;
  for (int i = tid; i < 3072; i += 256) Wl[i] = fcW[i];
  if (tid < 6) bl[tid] = fcb[tid];
  __syncthreads();
  int g = blockIdx.x * 256 + tid;  // 0..10239
  const f16* row = dec_out + (size_t)g * 512;
  float acc[6] = {0, 0, 0, 0, 0, 0};
  for (int kc = 0; kc < 64; kc++) {
    f16x8 xv = *(const f16x8*)&row[kc * 8];
#pragma unroll
    for (int j = 0; j < 8; j++) {
      float xf = (float)xv[j];
#pragma unroll
      for (int o = 0; o < 6; o++) acc[o] += xf * Wl[o * 512 + kc * 8 + j];
    }
  }
#pragma unroll
  for (int o = 0; o < 6; o++) out[(size_t)g * 6 + o] = acc[o] + bl[o];
}

extern "C" void kernel_launch(void* const* d_in, const int* in_sizes, int n_in,
                              void* d_out, int out_size, void* d_ws, size_t ws_size,
                              hipStream_t stream) {
  const float* x      = (const float*)d_in[0];
  const float* Wih0   = (const float*)d_in[1];
  const float* eWih32 = (const float*)d_in[2];
  const float* eWhh32 = (const float*)d_in[3];
  const float* ebih   = (const float*)d_in[4];
  const float* ebhh   = (const float*)d_in[5];
  const float* dWih32 = (const float*)d_in[6];
  const float* dWhh32 = (const float*)d_in[7];
  const float* dbih   = (const float*)d_in[8];
  const float* dbhh   = (const float*)d_in[9];
  const float* fcW    = (const float*)d_in[10];
  const float* fcb    = (const float*)d_in[11];
  float* outp = (float*)d_out;

  char* ws = (char*)d_ws;
  size_t off = 0;
  auto alloc = [&](size_t bytes) { void* p = ws + off; off += (bytes + 255) & ~255ULL; return p; };
  f16* eWih   = (f16*)alloc((size_t)3 * 262144 * 2);
  f16* eWhh   = (f16*)alloc((size_t)4 * 262144 * 2);
  f16* dWih   = (f16*)alloc((size_t)4 * 262144 * 2);
  f16* dWhh   = (f16*)alloc((size_t)4 * 262144 * 2);
  float* encB = (float*)alloc(2048 * 4);
  float* decB = (float*)alloc(2048 * 4);
  f16* hT     = (f16*)alloc((size_t)4 * 1024 * 512 * 2);
  f16* hstate = (f16*)alloc((size_t)8 * 1024 * 512 * 2);
  u64* hx     = (u64*)alloc((size_t)4 * 524288 * 8);   // 4 layers x 4 slots x 32c x 4096 u64
  f16* dec_o  = (f16*)alloc((size_t)1024 * 10 * 512 * 2);
  // sync block (contiguous, one memset): enc ctr + cons + dec ctr
  int* ctrE   = (int*)alloc(4 * 32 * 32 * 4);
  int* consA  = (int*)alloc(3 * 32 * 32 * 4);
  int* ctrD   = (int*)alloc(64 * 32 * 4);

  size_t syncsz = (char*)(ctrD + 64 * 32) - (char*)ctrE;
  hipMemsetAsync(ctrE, 0, syncsz, stream);

  k_cvt<<<512, 256, 0, stream>>>(eWih32, eWih, 3 * 262144);
  k_cvt<<<512, 256, 0, stream>>>(eWhh32, eWhh, 4 * 262144);
  k_cvt<<<512, 256, 0, stream>>>(dWih32, dWih, 4 * 262144);
  k_cvt<<<512, 256, 0, stream>>>(dWhh32, dWhh, 4 * 262144);
  k_bias<<<8, 256, 0, stream>>>(ebih, ebhh, encB, 2048);
  k_bias<<<8, 256, 0, stream>>>(dbih, dbhh, decB, 2048);

  // wavefront encoder: all 4 layers concurrent, consumer-side input transform
  k_enc_wave<<<512, 256, 0, stream>>>(x, Wih0, eWih, encB, eWhh, outp, hT, hx,
                                      ctrE, consA);
  k_dec_rec<<<256, 256, 0, stream>>>(dWih, dWhh, decB, hT, hstate, dec_o, ctrD);
  k_fc<<<40, 256, 0, stream>>>(dec_o, fcW, fcb, outp + (size_t)1024 * 128 * 512);
}